// Round 1
// baseline (277.552 us; speedup 1.0000x reference)
//
#include <hip/hip_runtime.h>
#include <math.h>

// ECDA loss, compacted per-class formulation.
// Inputs: clean_feats[2048,256] f32, noisy_feats[2048,256] f32,
//         clean_labels[2048] i32, noisy_labels[2048] i32,
//         noisy_mask[2048] f32, noisy_scores[2048] f32, class_weights[8] f32.
// Output: scalar f32.

static constexpr int NC = 8;      // classes
static constexpr int NN = 2048;   // items
static constexpr int DD = 256;    // dims

// workspace byte offsets
static constexpr int OFF_CNT_S = 0;        // 8 int
static constexpr int OFF_CNT_T = 64;       // 8 int
static constexpr int OFF_SW    = 128;      // 8 f32
static constexpr int OFF_SQS   = 192;      // 8 f32 (atomic accum)
static constexpr int OFF_SQT   = 256;      // 8 f32 (atomic accum)
static constexpr int OFF_INVBW = 384;      // 8*5 f32
static constexpr int OFF_SCC   = 576;      // 8 f32
static constexpr int OFF_SNN   = 640;      // 8 f32
static constexpr int OFF_SCN   = 704;      // 8 f32
static constexpr int OFF_VS    = 4096;     // 8*256 f32 (atomic accum)
static constexpr int OFF_VT    = 12288;    // 8*256 f32 (atomic accum)
static constexpr int OFF_IDX_S = 32768;    // 8*2048 int
static constexpr int OFF_IDX_T = 98304;    // 8*2048 int
static constexpr int OFF_WT    = 163840;   // 8*2048 f32
// total ~229 KB

__device__ inline float brs256(float v, float* sh4) {
  // block (256 thr) reduce-sum, result valid at tid 0. Callable repeatedly.
  for (int o = 32; o > 0; o >>= 1) v += __shfl_xor(v, o, 64);
  int w = threadIdx.x >> 6, ln = threadIdx.x & 63;
  __syncthreads();                    // protect sh4 reuse from previous call
  if (ln == 0) sh4[w] = v;
  __syncthreads();
  float r = 0.f;
  if (threadIdx.x == 0) r = sh4[0] + sh4[1] + sh4[2] + sh4[3];
  return r;
}

// K1: per-class compacted index lists (deterministic wave-ballot), counts,
// score sums; zero the moment accumulators.
__global__ __launch_bounds__(512) void k1_lists(
    const int* __restrict__ clab, const int* __restrict__ nlab,
    const float* __restrict__ nmask, const float* __restrict__ nscore,
    char* __restrict__ ws) {
  int tid = threadIdx.x;
  int wave = tid >> 6, lane = tid & 63;
  int*   cnt_s = (int*)(ws + OFF_CNT_S);
  int*   cnt_t = (int*)(ws + OFF_CNT_T);
  float* sw    = (float*)(ws + OFF_SW);
  int*   idx_s = (int*)(ws + OFF_IDX_S);
  int*   idx_t = (int*)(ws + OFF_IDX_T);
  float* wt    = (float*)(ws + OFF_WT);
  float* vacc  = (float*)(ws + OFF_VS);   // vs(2048 f) + vt(2048 f) contiguous
  float* sqs   = (float*)(ws + OFF_SQS);
  float* sqt   = (float*)(ws + OFF_SQT);

  for (int i = tid; i < 2 * NC * DD; i += 512) vacc[i] = 0.f;
  if (tid < NC) { sqs[tid] = 0.f; sqt[tid] = 0.f; }

  int c = wave;  // 8 waves, one class each
  {
    int base = 0;
    for (int it = 0; it < NN / 64; ++it) {
      int i = it * 64 + lane;
      bool m = (clab[i] == c);
      unsigned long long msk = __ballot(m);
      int pos = __popcll(msk & ((1ull << lane) - 1ull));
      if (m) idx_s[c * NN + base + pos] = i;
      base += __popcll(msk);
    }
    if (lane == 0) cnt_s[c] = base;
  }
  {
    int base = 0; float swa = 0.f;
    for (int it = 0; it < NN / 64; ++it) {
      int i = it * 64 + lane;
      bool m = (nlab[i] == c) && (nmask[i] > 0.5f);
      unsigned long long msk = __ballot(m);
      int pos = __popcll(msk & ((1ull << lane) - 1ull));
      float s = nscore[i];
      if (m) { idx_t[c * NN + base + pos] = i; wt[c * NN + base + pos] = s; swa += s; }
      base += __popcll(msk);
    }
    for (int o = 32; o > 0; o >>= 1) swa += __shfl_xor(swa, o, 64);
    if (lane == 0) { cnt_t[c] = base; sw[c] = swa; }
  }
}

// K2: per-class moments. 32 blocks = 8 classes x 4 member-chunks; thread = dim.
__global__ __launch_bounds__(256) void k2_moments(
    const float* __restrict__ cfeat, const float* __restrict__ nfeat,
    char* __restrict__ ws) {
  __shared__ float sh4[4];
  int c = blockIdx.x >> 2, q = blockIdx.x & 3;
  int d = threadIdx.x;
  const int* cnt_s = (const int*)(ws + OFF_CNT_S);
  const int* cnt_t = (const int*)(ws + OFF_CNT_T);
  const int* idx_s = (const int*)(ws + OFF_IDX_S);
  const int* idx_t = (const int*)(ws + OFF_IDX_T);
  float* vs  = (float*)(ws + OFF_VS);
  float* vt  = (float*)(ws + OFF_VT);
  float* sqs = (float*)(ws + OFF_SQS);
  float* sqt = (float*)(ws + OFF_SQT);

  {
    float va = 0.f, qa = 0.f;
    int ns = cnt_s[c];
    for (int m = q; m < ns; m += 4) {
      float v = cfeat[idx_s[c * NN + m] * DD + d];
      va += v; qa += v * v;
    }
    atomicAdd(&vs[c * DD + d], va);
    float t = brs256(qa, sh4);
    if (threadIdx.x == 0) atomicAdd(&sqs[c], t);
  }
  {
    float va = 0.f, qa = 0.f;
    int nt = cnt_t[c];
    for (int m = q; m < nt; m += 4) {
      float v = nfeat[idx_t[c * NN + m] * DD + d];
      va += v; qa += v * v;
    }
    atomicAdd(&vt[c * DD + d], va);
    float t = brs256(qa, sh4);
    if (threadIdx.x == 0) atomicAdd(&sqt[c], t);
  }
}

// K3: closed-form sumL2 -> bandwidths; compact, repulsion, attention, scales;
// writes the non-pairwise part of the loss to out[0].
__global__ __launch_bounds__(256) void k3_finalize(
    const float* __restrict__ cw, char* __restrict__ ws,
    float* __restrict__ out) {
  __shared__ float sh4[4];
  __shared__ float dss[NC], dtt[NC], dst[NC];
  __shared__ float dcen[28];
  int tid = threadIdx.x;
  const float* vs  = (const float*)(ws + OFF_VS);
  const float* vt  = (const float*)(ws + OFF_VT);
  const int* cnt_s = (const int*)(ws + OFF_CNT_S);
  const int* cnt_t = (const int*)(ws + OFF_CNT_T);
  const float* sw  = (const float*)(ws + OFF_SW);
  const float* sqs = (const float*)(ws + OFF_SQS);
  const float* sqt = (const float*)(ws + OFF_SQT);
  float* invbw = (float*)(ws + OFF_INVBW);
  float* scc   = (float*)(ws + OFF_SCC);
  float* snn   = (float*)(ws + OFF_SNN);
  float* scn   = (float*)(ws + OFF_SCN);

  for (int c = 0; c < NC; ++c) {
    float a = vs[c * DD + tid], b = vt[c * DD + tid];
    float r1 = brs256(a * a, sh4);
    float r2 = brs256(b * b, sh4);
    float r3 = brs256(a * b, sh4);
    if (tid == 0) { dss[c] = r1; dtt[c] = r2; dst[c] = r3; }
  }
  // centroid pairwise distances (28 pairs)
  int p = 0;
  for (int a = 0; a < NC; ++a) {
    for (int b = a + 1; b < NC; ++b) {
      float mxa = fmaxf((float)cnt_t[a], 1.f);
      float mxb = fmaxf((float)cnt_t[b], 1.f);
      float diff = vt[a * DD + tid] / mxa - vt[b * DD + tid] / mxb;
      float r = brs256(diff * diff, sh4);
      if (tid == 0) dcen[p] = sqrtf(fmaxf(r, 1e-12f));
      ++p;
    }
  }
  __syncthreads();
  if (tid == 0) {
    int nvalid = 0;
    for (int c = 0; c < NC; ++c) nvalid += (cnt_t[c] > 0);
    float sumD = 0.f; int np = 0; p = 0;
    for (int a = 0; a < NC; ++a)
      for (int b = a + 1; b < NC; ++b) {
        if (cnt_t[a] > 0 && cnt_t[b] > 0) { sumD += dcen[p]; ++np; }
        ++p;
      }
    float repl = (nvalid > 1) ? (-sumD / fmaxf((float)np, 1.f)) : 0.f;
    float meanw = 0.f;
    for (int c = 0; c < NC; ++c) meanw += cw[c];
    meanw *= (1.f / NC);
    float base = 0.f;
    for (int c = 0; c < NC; ++c) {
      float ns = (float)cnt_s[c], nt = (float)cnt_t[c];
      float n = ns + nt;
      float sumL2 = 2.f * ns * sqs[c] - 2.f * dss[c]
                  + 2.f * nt * sqt[c] - 2.f * dtt[c]
                  + 2.f * (nt * sqs[c] + ns * sqt[c] - 2.f * dst[c]);
      float bw0 = sumL2 / fmaxf(n * n - n, 1.f) * 0.25f;  // half = 2^(5/2 int)=4
      float mul = 1.f;
      for (int k = 0; k < 5; ++k) {
        invbw[c * 5 + k] = 1.f / (bw0 * mul + 1e-8f);
        mul *= 2.f;
      }
      float attn = expf(meanw - cw[c]);                    // LAMBDA = 1
      float coef = (cnt_s[c] >= 2 && cnt_t[c] >= 2) ? attn : 0.f;
      float swc = sw[c];
      scc[c] = coef / (ns * ns + 1e-8f);
      snn[c] = coef / (swc * swc + 1e-8f);
      scn[c] = -2.f * coef / (ns * swc + 1e-8f);
      float mx = fmaxf(nt, 1.f);
      float compact = (sqt[c] - 2.f * dtt[c] / mx + nt * dtt[c] / (mx * mx)) / mx;
      base += coef * (0.1f * compact + 0.01f * repl);
    }
    out[0] = base;
  }
}

// K4: within-class pairwise exp-kernel sums. 1536 blocks =
// type(3) x class(8) x rowchunk(64 of 32 rows), most early-exit.
// 32x32 pair tile in LDS (stride 33: conflict-free), 2x2 register tile.
__global__ __launch_bounds__(256) void k4_pairs(
    const float* __restrict__ cfeat, const float* __restrict__ nfeat,
    const char* __restrict__ ws, float* __restrict__ out) {
  __shared__ float la[32 * 33];
  __shared__ float lb[32 * 33];
  __shared__ float shred[4];
  int bid = blockIdx.x;
  int type = bid >> 9;        // 512 blocks per type
  int rem = bid & 511;
  int c = rem >> 6;
  int rchunk = rem & 63;

  const int* cnt_s = (const int*)(ws + OFF_CNT_S);
  const int* cnt_t = (const int*)(ws + OFF_CNT_T);
  const int* idx_s = (const int*)(ws + OFF_IDX_S);
  const int* idx_t = (const int*)(ws + OFF_IDX_T);
  const float* wt  = (const float*)(ws + OFF_WT);
  const float* scc = (const float*)(ws + OFF_SCC);
  const float* snn = (const float*)(ws + OFF_SNN);
  const float* scn = (const float*)(ws + OFF_SCN);
  const float* invbw = (const float*)(ws + OFF_INVBW);

  const int* pa; const int* pb;
  const float* fa; const float* fb;
  const float* wa = nullptr; const float* wb = nullptr;
  int na, nb; float scale;
  if (type == 0) {            // clean x clean
    pa = idx_s + c * NN; pb = pa; na = nb = cnt_s[c];
    fa = cfeat; fb = cfeat; scale = scc[c];
  } else if (type == 1) {     // noisy x noisy (weighted both sides)
    pa = idx_t + c * NN; pb = pa; na = nb = cnt_t[c];
    fa = nfeat; fb = nfeat; wa = wt + c * NN; wb = wa; scale = snn[c];
  } else {                    // clean x noisy (weighted col side)
    pa = idx_s + c * NN; na = cnt_s[c];
    pb = idx_t + c * NN; nb = cnt_t[c];
    fa = cfeat; fb = nfeat; wb = wt + c * NN; scale = scn[c];
  }
  int rbase = rchunk * 32;
  if (scale == 0.f || rbase >= na || nb == 0) return;

  float ib0 = invbw[c * 5 + 0], ib1 = invbw[c * 5 + 1], ib2 = invbw[c * 5 + 2];
  float ib3 = invbw[c * 5 + 3], ib4 = invbw[c * 5 + 4];

  int ty = threadIdx.x >> 4, tx = threadIdx.x & 15;
  float partial = 0.f;

  for (int jb = 0; jb < nb; jb += 32) {
    float a00 = 0.f, a01 = 0.f, a10 = 0.f, a11 = 0.f;
    for (int dc = 0; dc < DD; dc += 32) {
      for (int e = threadIdx.x; e < 1024; e += 256) {
        int r = e >> 5, dd = e & 31;
        int gr = rbase + r;
        float v = 0.f;
        if (gr < na) v = fa[pa[gr] * DD + dc + dd];
        la[r * 33 + dd] = v;
        int gc = jb + r;
        float u = 0.f;
        if (gc < nb) u = fb[pb[gc] * DD + dc + dd];
        lb[r * 33 + dd] = u;
      }
      __syncthreads();
#pragma unroll
      for (int d = 0; d < 32; ++d) {
        float A0 = la[(2 * ty) * 33 + d];
        float A1 = la[(2 * ty + 1) * 33 + d];
        float B0 = lb[(2 * tx) * 33 + d];
        float B1 = lb[(2 * tx + 1) * 33 + d];
        float t;
        t = A0 - B0; a00 += t * t;
        t = A0 - B1; a01 += t * t;
        t = A1 - B0; a10 += t * t;
        t = A1 - B1; a11 += t * t;
      }
      __syncthreads();
    }
    int i0 = rbase + 2 * ty, i1 = i0 + 1;
    int j0 = jb + 2 * tx, j1 = j0 + 1;
    float d2s[4] = {a00, a01, a10, a11};
    int is[4] = {i0, i0, i1, i1};
    int js[4] = {j0, j1, j0, j1};
#pragma unroll
    for (int u = 0; u < 4; ++u) {
      int i = is[u], j = js[u];
      if (i < na && j < nb) {
        float w = 1.f;
        if (type == 1) w = wa[i] * wb[j];
        else if (type == 2) w = wb[j];
        float d2 = d2s[u];
        float e = __expf(-d2 * ib0) + __expf(-d2 * ib1) + __expf(-d2 * ib2)
                + __expf(-d2 * ib3) + __expf(-d2 * ib4);
        partial += w * e;
      }
    }
  }
  for (int o = 32; o > 0; o >>= 1) partial += __shfl_xor(partial, o, 64);
  int w64 = threadIdx.x >> 6, ln = threadIdx.x & 63;
  if (ln == 0) shred[w64] = partial;
  __syncthreads();
  if (threadIdx.x == 0) {
    float tot = shred[0] + shred[1] + shred[2] + shred[3];
    atomicAdd(out, scale * tot);
  }
}

extern "C" void kernel_launch(void* const* d_in, const int* in_sizes, int n_in,
                              void* d_out, int out_size, void* d_ws, size_t ws_size,
                              hipStream_t stream) {
  const float* cfeat  = (const float*)d_in[0];
  const float* nfeat  = (const float*)d_in[1];
  const int*   clab   = (const int*)d_in[2];
  const int*   nlab   = (const int*)d_in[3];
  const float* nmask  = (const float*)d_in[4];
  const float* nscore = (const float*)d_in[5];
  const float* cw     = (const float*)d_in[6];
  float* out = (float*)d_out;
  char* ws = (char*)d_ws;

  k1_lists<<<1, 512, 0, stream>>>(clab, nlab, nmask, nscore, ws);
  k2_moments<<<32, 256, 0, stream>>>(cfeat, nfeat, ws);
  k3_finalize<<<1, 256, 0, stream>>>(cw, ws, out);
  k4_pairs<<<3 * 8 * 64, 256, 0, stream>>>(cfeat, nfeat, ws, out);
}

// Round 2
// 108.732 us; speedup vs baseline: 2.5526x; 2.5526x over previous
//
#include <hip/hip_runtime.h>
#include <math.h>

// ECDA loss, compacted per-class formulation.
// Inputs: clean_feats[2048,256] f32, noisy_feats[2048,256] f32,
//         clean_labels[2048] i32, noisy_labels[2048] i32,
//         noisy_mask[2048] f32, noisy_scores[2048] f32, class_weights[8] f32.
// Output: scalar f32.

static constexpr int NC = 8;      // classes
static constexpr int NN = 2048;   // items
static constexpr int DD = 256;    // dims

// workspace byte offsets
static constexpr int OFF_CNT_S = 0;        // 8 int
static constexpr int OFF_CNT_T = 64;       // 8 int
static constexpr int OFF_SW    = 128;      // 8 f32
static constexpr int OFF_SQS   = 192;      // 8 f32 (atomic accum)
static constexpr int OFF_SQT   = 256;      // 8 f32 (atomic accum)
static constexpr int OFF_INVBW = 384;      // 8*5 f32
static constexpr int OFF_SCC   = 576;      // 8 f32
static constexpr int OFF_SNN   = 640;      // 8 f32
static constexpr int OFF_SCN   = 704;      // 8 f32
static constexpr int OFF_VS    = 4096;     // 8*256 f32 (atomic accum)
static constexpr int OFF_VT    = 12288;    // 8*256 f32 (atomic accum)
static constexpr int OFF_IDX_S = 32768;    // 8*2048 int
static constexpr int OFF_IDX_T = 98304;    // 8*2048 int
static constexpr int OFF_WT    = 163840;   // 8*2048 f32
// total ~229 KB

__device__ inline float brs256(float v, float* sh4) {
  // block (256 thr) reduce-sum, result valid at tid 0. Callable repeatedly.
  for (int o = 32; o > 0; o >>= 1) v += __shfl_xor(v, o, 64);
  int w = threadIdx.x >> 6, ln = threadIdx.x & 63;
  __syncthreads();                    // protect sh4 reuse from previous call
  if (ln == 0) sh4[w] = v;
  __syncthreads();
  float r = 0.f;
  if (threadIdx.x == 0) r = sh4[0] + sh4[1] + sh4[2] + sh4[3];
  return r;
}

// K1: per-class compacted index lists (deterministic wave-ballot), counts,
// score sums; zero the moment accumulators.
__global__ __launch_bounds__(512) void k1_lists(
    const int* __restrict__ clab, const int* __restrict__ nlab,
    const float* __restrict__ nmask, const float* __restrict__ nscore,
    char* __restrict__ ws) {
  int tid = threadIdx.x;
  int wave = tid >> 6, lane = tid & 63;
  int*   cnt_s = (int*)(ws + OFF_CNT_S);
  int*   cnt_t = (int*)(ws + OFF_CNT_T);
  float* sw    = (float*)(ws + OFF_SW);
  int*   idx_s = (int*)(ws + OFF_IDX_S);
  int*   idx_t = (int*)(ws + OFF_IDX_T);
  float* wt    = (float*)(ws + OFF_WT);
  float* vacc  = (float*)(ws + OFF_VS);   // vs(2048 f) + vt(2048 f) contiguous
  float* sqs   = (float*)(ws + OFF_SQS);
  float* sqt   = (float*)(ws + OFF_SQT);

  for (int i = tid; i < 2 * NC * DD; i += 512) vacc[i] = 0.f;
  if (tid < NC) { sqs[tid] = 0.f; sqt[tid] = 0.f; }

  int c = wave;  // 8 waves, one class each
  {
    int base = 0;
    for (int it = 0; it < NN / 64; ++it) {
      int i = it * 64 + lane;
      bool m = (clab[i] == c);
      unsigned long long msk = __ballot(m);
      int pos = __popcll(msk & ((1ull << lane) - 1ull));
      if (m) idx_s[c * NN + base + pos] = i;
      base += __popcll(msk);
    }
    if (lane == 0) cnt_s[c] = base;
  }
  {
    int base = 0; float swa = 0.f;
    for (int it = 0; it < NN / 64; ++it) {
      int i = it * 64 + lane;
      bool m = (nlab[i] == c) && (nmask[i] > 0.5f);
      unsigned long long msk = __ballot(m);
      int pos = __popcll(msk & ((1ull << lane) - 1ull));
      float s = nscore[i];
      if (m) { idx_t[c * NN + base + pos] = i; wt[c * NN + base + pos] = s; swa += s; }
      base += __popcll(msk);
    }
    for (int o = 32; o > 0; o >>= 1) swa += __shfl_xor(swa, o, 64);
    if (lane == 0) { cnt_t[c] = base; sw[c] = swa; }
  }
}

// K2: per-class moments. 32 blocks = 8 classes x 4 member-chunks; thread = dim.
__global__ __launch_bounds__(256) void k2_moments(
    const float* __restrict__ cfeat, const float* __restrict__ nfeat,
    char* __restrict__ ws) {
  __shared__ float sh4[4];
  int c = blockIdx.x >> 2, q = blockIdx.x & 3;
  int d = threadIdx.x;
  const int* cnt_s = (const int*)(ws + OFF_CNT_S);
  const int* cnt_t = (const int*)(ws + OFF_CNT_T);
  const int* idx_s = (const int*)(ws + OFF_IDX_S);
  const int* idx_t = (const int*)(ws + OFF_IDX_T);
  float* vs  = (float*)(ws + OFF_VS);
  float* vt  = (float*)(ws + OFF_VT);
  float* sqs = (float*)(ws + OFF_SQS);
  float* sqt = (float*)(ws + OFF_SQT);

  {
    float va = 0.f, qa = 0.f;
    int ns = cnt_s[c];
    for (int m = q; m < ns; m += 4) {
      float v = cfeat[idx_s[c * NN + m] * DD + d];
      va += v; qa += v * v;
    }
    atomicAdd(&vs[c * DD + d], va);
    float t = brs256(qa, sh4);
    if (threadIdx.x == 0) atomicAdd(&sqs[c], t);
  }
  {
    float va = 0.f, qa = 0.f;
    int nt = cnt_t[c];
    for (int m = q; m < nt; m += 4) {
      float v = nfeat[idx_t[c * NN + m] * DD + d];
      va += v; qa += v * v;
    }
    atomicAdd(&vt[c * DD + d], va);
    float t = brs256(qa, sh4);
    if (threadIdx.x == 0) atomicAdd(&sqt[c], t);
  }
}

// K3: closed-form sumL2 -> bandwidths; compact, repulsion, attention, scales;
// writes the non-pairwise part of the loss to out[0].
__global__ __launch_bounds__(256) void k3_finalize(
    const float* __restrict__ cw, char* __restrict__ ws,
    float* __restrict__ out) {
  __shared__ float sh4[4];
  __shared__ float dss[NC], dtt[NC], dst[NC];
  __shared__ float dcen[28];
  int tid = threadIdx.x;
  const float* vs  = (const float*)(ws + OFF_VS);
  const float* vt  = (const float*)(ws + OFF_VT);
  const int* cnt_s = (const int*)(ws + OFF_CNT_S);
  const int* cnt_t = (const int*)(ws + OFF_CNT_T);
  const float* sw  = (const float*)(ws + OFF_SW);
  const float* sqs = (const float*)(ws + OFF_SQS);
  const float* sqt = (const float*)(ws + OFF_SQT);
  float* invbw = (float*)(ws + OFF_INVBW);
  float* scc   = (float*)(ws + OFF_SCC);
  float* snn   = (float*)(ws + OFF_SNN);
  float* scn   = (float*)(ws + OFF_SCN);

  for (int c = 0; c < NC; ++c) {
    float a = vs[c * DD + tid], b = vt[c * DD + tid];
    float r1 = brs256(a * a, sh4);
    float r2 = brs256(b * b, sh4);
    float r3 = brs256(a * b, sh4);
    if (tid == 0) { dss[c] = r1; dtt[c] = r2; dst[c] = r3; }
  }
  // centroid pairwise distances (28 pairs)
  int p = 0;
  for (int a = 0; a < NC; ++a) {
    for (int b = a + 1; b < NC; ++b) {
      float mxa = fmaxf((float)cnt_t[a], 1.f);
      float mxb = fmaxf((float)cnt_t[b], 1.f);
      float diff = vt[a * DD + tid] / mxa - vt[b * DD + tid] / mxb;
      float r = brs256(diff * diff, sh4);
      if (tid == 0) dcen[p] = sqrtf(fmaxf(r, 1e-12f));
      ++p;
    }
  }
  __syncthreads();
  if (tid == 0) {
    int nvalid = 0;
    for (int c = 0; c < NC; ++c) nvalid += (cnt_t[c] > 0);
    float sumD = 0.f; int np = 0; p = 0;
    for (int a = 0; a < NC; ++a)
      for (int b = a + 1; b < NC; ++b) {
        if (cnt_t[a] > 0 && cnt_t[b] > 0) { sumD += dcen[p]; ++np; }
        ++p;
      }
    float repl = (nvalid > 1) ? (-sumD / fmaxf((float)np, 1.f)) : 0.f;
    float meanw = 0.f;
    for (int c = 0; c < NC; ++c) meanw += cw[c];
    meanw *= (1.f / NC);
    float base = 0.f;
    for (int c = 0; c < NC; ++c) {
      float ns = (float)cnt_s[c], nt = (float)cnt_t[c];
      float n = ns + nt;
      float sumL2 = 2.f * ns * sqs[c] - 2.f * dss[c]
                  + 2.f * nt * sqt[c] - 2.f * dtt[c]
                  + 2.f * (nt * sqs[c] + ns * sqt[c] - 2.f * dst[c]);
      float bw0 = sumL2 / fmaxf(n * n - n, 1.f) * 0.25f;  // half = 2^(5/2 int)=4
      float mul = 1.f;
      for (int k = 0; k < 5; ++k) {
        invbw[c * 5 + k] = 1.f / (bw0 * mul + 1e-8f);
        mul *= 2.f;
      }
      float attn = expf(meanw - cw[c]);                    // LAMBDA = 1
      float coef = (cnt_s[c] >= 2 && cnt_t[c] >= 2) ? attn : 0.f;
      float swc = sw[c];
      scc[c] = coef / (ns * ns + 1e-8f);
      snn[c] = coef / (swc * swc + 1e-8f);
      scn[c] = -2.f * coef / (ns * swc + 1e-8f);
      float mx = fmaxf(nt, 1.f);
      float compact = (sqt[c] - 2.f * dtt[c] / mx + nt * dtt[c] / (mx * mx)) / mx;
      base += coef * (0.1f * compact + 0.01f * repl);
    }
    out[0] = base;
  }
}

// K4: within-class pairwise exp-kernel sums. 1536 blocks =
// type(3) x class(8) x rtile(8) x ctile(8); one 32x32 pair tile per block.
// cc/nn are symmetric: lower-triangle tiles skipped, upper-triangle doubled.
// LDS tiles are d-major (stride 34, even) so each thread reads its two
// rows/cols as one aligned float2 (ds_read_b64, conflict-free).
__global__ __launch_bounds__(256) void k4_pairs(
    const float* __restrict__ cfeat, const float* __restrict__ nfeat,
    const char* __restrict__ ws, float* __restrict__ out) {
  __shared__ float la[32 * 34];
  __shared__ float lb[32 * 34];
  __shared__ float shred[4];
  int bid = blockIdx.x;
  int type  = bid >> 9;       // 512 blocks per type
  int c     = (bid >> 6) & 7;
  int rtile = (bid >> 3) & 7;
  int ctile = bid & 7;

  if (type <= 1 && ctile < rtile) return;   // symmetric types: upper only

  const int* cnt_s = (const int*)(ws + OFF_CNT_S);
  const int* cnt_t = (const int*)(ws + OFF_CNT_T);
  const int* idx_s = (const int*)(ws + OFF_IDX_S);
  const int* idx_t = (const int*)(ws + OFF_IDX_T);
  const float* wt  = (const float*)(ws + OFF_WT);
  const float* scc = (const float*)(ws + OFF_SCC);
  const float* snn = (const float*)(ws + OFF_SNN);
  const float* scn = (const float*)(ws + OFF_SCN);
  const float* invbw = (const float*)(ws + OFF_INVBW);

  const int* pa; const int* pb;
  const float* fa; const float* fb;
  const float* wa = nullptr; const float* wb = nullptr;
  int na, nb; float scale;
  if (type == 0) {            // clean x clean
    pa = idx_s + c * NN; pb = pa; na = nb = cnt_s[c];
    fa = cfeat; fb = cfeat; scale = scc[c];
  } else if (type == 1) {     // noisy x noisy (weighted both sides)
    pa = idx_t + c * NN; pb = pa; na = nb = cnt_t[c];
    fa = nfeat; fb = nfeat; wa = wt + c * NN; wb = wa; scale = snn[c];
  } else {                    // clean x noisy (weighted col side)
    pa = idx_s + c * NN; na = cnt_s[c];
    pb = idx_t + c * NN; nb = cnt_t[c];
    fa = cfeat; fb = nfeat; wb = wt + c * NN; scale = scn[c];
  }
  int rbase = rtile * 32, cbase = ctile * 32;
  if (scale == 0.f || rbase >= na || cbase >= nb) return;
  float factor = (type <= 1 && ctile > rtile) ? 2.f : 1.f;

  float ib0 = invbw[c * 5 + 0], ib1 = invbw[c * 5 + 1], ib2 = invbw[c * 5 + 2];
  float ib3 = invbw[c * 5 + 3], ib4 = invbw[c * 5 + 4];

  int ty = threadIdx.x >> 4, tx = threadIdx.x & 15;   // 16x16 threads, 2x2 out

  float a00 = 0.f, a01 = 0.f, a10 = 0.f, a11 = 0.f;
  for (int dc = 0; dc < DD; dc += 32) {
    for (int e = threadIdx.x; e < 1024; e += 256) {
      int r = e >> 5, dd = e & 31;        // consecutive tid -> consecutive dd
      int gr = rbase + r;
      float v = 0.f;
      if (gr < na) v = fa[pa[gr] * DD + dc + dd];
      la[dd * 34 + r] = v;
      int gc = cbase + r;
      float u = 0.f;
      if (gc < nb) u = fb[pb[gc] * DD + dc + dd];
      lb[dd * 34 + r] = u;
    }
    __syncthreads();
#pragma unroll
    for (int d = 0; d < 32; ++d) {
      float2 A = *(const float2*)&la[d * 34 + 2 * ty];
      float2 B = *(const float2*)&lb[d * 34 + 2 * tx];
      float t;
      t = A.x - B.x; a00 += t * t;
      t = A.x - B.y; a01 += t * t;
      t = A.y - B.x; a10 += t * t;
      t = A.y - B.y; a11 += t * t;
    }
    __syncthreads();
  }

  int i0 = rbase + 2 * ty, i1 = i0 + 1;
  int j0 = cbase + 2 * tx, j1 = j0 + 1;
  float d2s[4] = {a00, a01, a10, a11};
  int is[4] = {i0, i0, i1, i1};
  int js[4] = {j0, j1, j0, j1};
  float partial = 0.f;
#pragma unroll
  for (int u = 0; u < 4; ++u) {
    int i = is[u], j = js[u];
    if (i < na && j < nb) {
      float w = 1.f;
      if (type == 1) w = wa[i] * wb[j];
      else if (type == 2) w = wb[j];
      float d2 = d2s[u];
      float e = __expf(-d2 * ib0) + __expf(-d2 * ib1) + __expf(-d2 * ib2)
              + __expf(-d2 * ib3) + __expf(-d2 * ib4);
      partial += w * e;
    }
  }
  for (int o = 32; o > 0; o >>= 1) partial += __shfl_xor(partial, o, 64);
  int w64 = threadIdx.x >> 6, ln = threadIdx.x & 63;
  if (ln == 0) shred[w64] = partial;
  __syncthreads();
  if (threadIdx.x == 0) {
    float tot = shred[0] + shred[1] + shred[2] + shred[3];
    atomicAdd(out, scale * factor * tot);
  }
}

extern "C" void kernel_launch(void* const* d_in, const int* in_sizes, int n_in,
                              void* d_out, int out_size, void* d_ws, size_t ws_size,
                              hipStream_t stream) {
  const float* cfeat  = (const float*)d_in[0];
  const float* nfeat  = (const float*)d_in[1];
  const int*   clab   = (const int*)d_in[2];
  const int*   nlab   = (const int*)d_in[3];
  const float* nmask  = (const float*)d_in[4];
  const float* nscore = (const float*)d_in[5];
  const float* cw     = (const float*)d_in[6];
  float* out = (float*)d_out;
  char* ws = (char*)d_ws;

  k1_lists<<<1, 512, 0, stream>>>(clab, nlab, nmask, nscore, ws);
  k2_moments<<<32, 256, 0, stream>>>(cfeat, nfeat, ws);
  k3_finalize<<<1, 256, 0, stream>>>(cw, ws, out);
  k4_pairs<<<3 * 8 * 64, 256, 0, stream>>>(cfeat, nfeat, ws, out);
}

// Round 3
// 59.447 us; speedup vs baseline: 4.6689x; 1.8291x over previous
//
#include <hip/hip_runtime.h>
#include <math.h>

// ECDA loss, compacted per-class formulation, MFMA pairwise core.
// Inputs: clean_feats[2048,256] f32, noisy_feats[2048,256] f32,
//         clean_labels[2048] i32, noisy_labels[2048] i32,
//         noisy_mask[2048] f32, noisy_scores[2048] f32, class_weights[8] f32.
// Output: scalar f32.

static constexpr int NC = 8;
static constexpr int NN = 2048;
static constexpr int DD = 256;

// workspace byte offsets
static constexpr int OFF_CNT_S = 0;        // 8 int
static constexpr int OFF_CNT_T = 64;       // 8 int
static constexpr int OFF_SW    = 128;      // 8 f32
static constexpr int OFF_SQS   = 192;      // 8 f32 (atomic accum)
static constexpr int OFF_SQT   = 256;      // 8 f32 (atomic accum)
static constexpr int OFF_INVBW = 384;      // 8*5 f32
static constexpr int OFF_SCC   = 576;      // 8 f32
static constexpr int OFF_SNN   = 640;      // 8 f32
static constexpr int OFF_SCN   = 704;      // 8 f32
static constexpr int OFF_VS    = 4096;     // 8*256 f32 (atomic accum)
static constexpr int OFF_VT    = 12288;    // 8*256 f32 (atomic accum)
static constexpr int OFF_IDX_S = 32768;    // 8*2048 int
static constexpr int OFF_IDX_T = 98304;    // 8*2048 int
static constexpr int OFF_WT    = 163840;   // 8*2048 f32
static constexpr int OFF_QNS   = 229376;   // 8*2048 f32 per-position norms (clean)
static constexpr int OFF_QNT   = 294912;   // 8*2048 f32 per-position norms (noisy)
// total ~352 KB

typedef __attribute__((ext_vector_type(8))) short bf16x8;
typedef __attribute__((ext_vector_type(4))) float f32x4;

__device__ inline float wred64(float v) {
  for (int o = 32; o > 0; o >>= 1) v += __shfl_xor(v, o, 64);
  return v;
}
// RNE round f32 -> bf16 (bits), and round-to-bf16-then-back as f32.
__device__ inline short f2bf(float x) {
  unsigned u = __float_as_uint(x);
  return (short)((u + 0x7fffu + ((u >> 16) & 1u)) >> 16);
}
__device__ inline float rbf(float x) {
  unsigned u = __float_as_uint(x);
  u = (u + 0x7fffu + ((u >> 16) & 1u)) & 0xffff0000u;
  return __uint_as_float(u);
}

// K1: per-class compacted index lists (wave-ballot), counts, score sums;
// zero the moment accumulators. Labels preloaded into registers so the
// 32-iteration ballot chain is VALU-only (no per-iter dependent loads).
__global__ __launch_bounds__(512) void k1_lists(
    const int* __restrict__ clab, const int* __restrict__ nlab,
    const float* __restrict__ nmask, const float* __restrict__ nscore,
    char* __restrict__ ws) {
  int tid = threadIdx.x;
  int wave = tid >> 6, lane = tid & 63;
  int*   cnt_s = (int*)(ws + OFF_CNT_S);
  int*   cnt_t = (int*)(ws + OFF_CNT_T);
  float* sw    = (float*)(ws + OFF_SW);
  int*   idx_s = (int*)(ws + OFF_IDX_S);
  int*   idx_t = (int*)(ws + OFF_IDX_T);
  float* wt    = (float*)(ws + OFF_WT);
  float* vacc  = (float*)(ws + OFF_VS);   // vs + vt contiguous (4096 f32)
  float* sqs   = (float*)(ws + OFF_SQS);
  float* sqt   = (float*)(ws + OFF_SQT);

  for (int i = tid; i < 2 * NC * DD; i += 512) vacc[i] = 0.f;
  if (tid < NC) { sqs[tid] = 0.f; sqt[tid] = 0.f; }

  int c = wave;  // 8 waves, one class each
  {
    int lv[32];
#pragma unroll
    for (int it = 0; it < 32; ++it) lv[it] = clab[it * 64 + lane];
    int base = 0;
#pragma unroll
    for (int it = 0; it < 32; ++it) {
      bool m = (lv[it] == c);
      unsigned long long msk = __ballot(m);
      int pos = __popcll(msk & ((1ull << lane) - 1ull));
      if (m) idx_s[c * NN + base + pos] = it * 64 + lane;
      base += __popcll(msk);
    }
    if (lane == 0) cnt_s[c] = base;
  }
  {
    int lv[32]; float mv[32]; float sv[32];
#pragma unroll
    for (int it = 0; it < 32; ++it) {
      int i = it * 64 + lane;
      lv[it] = nlab[i]; mv[it] = nmask[i]; sv[it] = nscore[i];
    }
    int base = 0; float swa = 0.f;
#pragma unroll
    for (int it = 0; it < 32; ++it) {
      bool m = (lv[it] == c) && (mv[it] > 0.5f);
      unsigned long long msk = __ballot(m);
      int pos = __popcll(msk & ((1ull << lane) - 1ull));
      if (m) { idx_t[c * NN + base + pos] = it * 64 + lane;
               wt[c * NN + base + pos] = sv[it]; swa += sv[it]; }
      base += __popcll(msk);
    }
    swa = wred64(swa);
    if (lane == 0) { cnt_t[c] = base; sw[c] = swa; }
  }
}

// K2: per-class moments + per-position norms (of bf16-rounded rows).
// 256 blocks = 8 classes x 32 chunks; 4 waves per block each own one member
// at a time (float4 per lane over 256 dims).
__global__ __launch_bounds__(256) void k2_moments(
    const float* __restrict__ cfeat, const float* __restrict__ nfeat,
    char* __restrict__ ws) {
  __shared__ float sh[4 * 256];
  __shared__ float shq[4];
  int c = blockIdx.x >> 5, chunk = blockIdx.x & 31;
  int tid = threadIdx.x, mm = tid >> 6, lane = tid & 63;
  int d4 = lane * 4;
  const int* cnt_s = (const int*)(ws + OFF_CNT_S);
  const int* cnt_t = (const int*)(ws + OFF_CNT_T);
  const int* idx_s = (const int*)(ws + OFF_IDX_S);
  const int* idx_t = (const int*)(ws + OFF_IDX_T);
  float* vs  = (float*)(ws + OFF_VS);
  float* vt  = (float*)(ws + OFF_VT);
  float* sqs = (float*)(ws + OFF_SQS);
  float* sqt = (float*)(ws + OFF_SQT);
  float* qnS = (float*)(ws + OFF_QNS);
  float* qnT = (float*)(ws + OFF_QNT);

  // ---- clean ----
  {
    float vx = 0.f, vy = 0.f, vz = 0.f, vw = 0.f, qa = 0.f;
    int ns = cnt_s[c];
    for (int m = chunk + 32 * mm; m < ns; m += 128) {
      int item = idx_s[c * NN + m];
      float4 v = *(const float4*)&cfeat[item * DD + d4];
      vx += v.x; vy += v.y; vz += v.z; vw += v.w;
      qa += v.x * v.x + v.y * v.y + v.z * v.z + v.w * v.w;
      float rx = rbf(v.x), ry = rbf(v.y), rz = rbf(v.z), rw = rbf(v.w);
      float qr = wred64(rx * rx + ry * ry + rz * rz + rw * rw);
      if (lane == 0) qnS[c * NN + m] = qr;
    }
    sh[mm * 256 + d4 + 0] = vx; sh[mm * 256 + d4 + 1] = vy;
    sh[mm * 256 + d4 + 2] = vz; sh[mm * 256 + d4 + 3] = vw;
    qa = wred64(qa);
    if (lane == 0) shq[mm] = qa;
    __syncthreads();
    float s = sh[tid] + sh[256 + tid] + sh[512 + tid] + sh[768 + tid];
    atomicAdd(&vs[c * DD + tid], s);
    if (tid == 0) atomicAdd(&sqs[c], shq[0] + shq[1] + shq[2] + shq[3]);
    __syncthreads();
  }
  // ---- noisy ----
  {
    float vx = 0.f, vy = 0.f, vz = 0.f, vw = 0.f, qa = 0.f;
    int nt = cnt_t[c];
    for (int m = chunk + 32 * mm; m < nt; m += 128) {
      int item = idx_t[c * NN + m];
      float4 v = *(const float4*)&nfeat[item * DD + d4];
      vx += v.x; vy += v.y; vz += v.z; vw += v.w;
      qa += v.x * v.x + v.y * v.y + v.z * v.z + v.w * v.w;
      float rx = rbf(v.x), ry = rbf(v.y), rz = rbf(v.z), rw = rbf(v.w);
      float qr = wred64(rx * rx + ry * ry + rz * rz + rw * rw);
      if (lane == 0) qnT[c * NN + m] = qr;
    }
    sh[mm * 256 + d4 + 0] = vx; sh[mm * 256 + d4 + 1] = vy;
    sh[mm * 256 + d4 + 2] = vz; sh[mm * 256 + d4 + 3] = vw;
    qa = wred64(qa);
    if (lane == 0) shq[mm] = qa;
    __syncthreads();
    float s = sh[tid] + sh[256 + tid] + sh[512 + tid] + sh[768 + tid];
    atomicAdd(&vt[c * DD + tid], s);
    if (tid == 0) atomicAdd(&sqt[c], shq[0] + shq[1] + shq[2] + shq[3]);
  }
}

// K3: wave-parallel reductions (no per-task block barriers), then finale.
__global__ __launch_bounds__(256) void k3_finalize(
    const float* __restrict__ cw, char* __restrict__ ws,
    float* __restrict__ out) {
  __shared__ float dss[NC], dtt[NC], dst[NC];
  __shared__ float dcen[28];
  int tid = threadIdx.x, w = tid >> 6, lane = tid & 63;
  const float* vs  = (const float*)(ws + OFF_VS);
  const float* vt  = (const float*)(ws + OFF_VT);
  const int* cnt_s = (const int*)(ws + OFF_CNT_S);
  const int* cnt_t = (const int*)(ws + OFF_CNT_T);
  const float* sw  = (const float*)(ws + OFF_SW);
  const float* sqs = (const float*)(ws + OFF_SQS);
  const float* sqt = (const float*)(ws + OFF_SQT);
  float* invbw = (float*)(ws + OFF_INVBW);
  float* scc   = (float*)(ws + OFF_SCC);
  float* snn   = (float*)(ws + OFF_SNN);
  float* scn   = (float*)(ws + OFF_SCN);

  // 24 self/cross vector dots: t = c*3 + kind
  for (int t = w; t < 24; t += 4) {
    int c = t / 3, kind = t - c * 3;
    const float* xa = (kind == 1) ? (vt + c * DD) : (vs + c * DD);
    const float* ya = (kind == 0) ? (vs + c * DD) : (vt + c * DD);
    float4 x = *(const float4*)&xa[lane * 4];
    float4 y = *(const float4*)&ya[lane * 4];
    float s = wred64(x.x * y.x + x.y * y.y + x.z * y.z + x.w * y.w);
    if (lane == 0) {
      if (kind == 0) dss[c] = s; else if (kind == 1) dtt[c] = s; else dst[c] = s;
    }
  }
  // 28 centroid pair distances
  for (int t = w; t < 28; t += 4) {
    int a = 0, r = t;
    while (r >= 7 - a) { r -= 7 - a; ++a; }
    int b = a + 1 + r;
    float ima = 1.f / fmaxf((float)cnt_t[a], 1.f);
    float imb = 1.f / fmaxf((float)cnt_t[b], 1.f);
    float4 x = *(const float4*)&vt[a * DD + lane * 4];
    float4 y = *(const float4*)&vt[b * DD + lane * 4];
    float dx = x.x * ima - y.x * imb, dy = x.y * ima - y.y * imb;
    float dz = x.z * ima - y.z * imb, dw = x.w * ima - y.w * imb;
    float s = wred64(dx * dx + dy * dy + dz * dz + dw * dw);
    if (lane == 0) dcen[t] = sqrtf(fmaxf(s, 1e-12f));
  }
  __syncthreads();
  if (tid == 0) {
    int nvalid = 0;
    for (int c = 0; c < NC; ++c) nvalid += (cnt_t[c] > 0);
    float sumD = 0.f; int np = 0; int p = 0;
    for (int a = 0; a < NC; ++a)
      for (int b = a + 1; b < NC; ++b) {
        if (cnt_t[a] > 0 && cnt_t[b] > 0) { sumD += dcen[p]; ++np; }
        ++p;
      }
    float repl = (nvalid > 1) ? (-sumD / fmaxf((float)np, 1.f)) : 0.f;
    float meanw = 0.f;
    for (int c = 0; c < NC; ++c) meanw += cw[c];
    meanw *= (1.f / NC);
    float base = 0.f;
    for (int c = 0; c < NC; ++c) {
      float ns = (float)cnt_s[c], nt = (float)cnt_t[c];
      float n = ns + nt;
      float sumL2 = 2.f * ns * sqs[c] - 2.f * dss[c]
                  + 2.f * nt * sqt[c] - 2.f * dtt[c]
                  + 2.f * (nt * sqs[c] + ns * sqt[c] - 2.f * dst[c]);
      float bw0 = sumL2 / fmaxf(n * n - n, 1.f) * 0.25f;  // /half, half=4
      float mul = 1.f;
      for (int k = 0; k < 5; ++k) {
        invbw[c * 5 + k] = 1.f / (bw0 * mul + 1e-8f);
        mul *= 2.f;
      }
      float attn = expf(meanw - cw[c]);                    // LAMBDA = 1
      float coef = (cnt_s[c] >= 2 && cnt_t[c] >= 2) ? attn : 0.f;
      float swc = sw[c];
      scc[c] = coef / (ns * ns + 1e-8f);
      snn[c] = coef / (swc * swc + 1e-8f);
      scn[c] = -2.f * coef / (ns * swc + 1e-8f);
      float mx = fmaxf(nt, 1.f);
      float compact = (sqt[c] - 2.f * dtt[c] / mx + nt * dtt[c] / (mx * mx)) / mx;
      base += coef * (0.1f * compact + 0.01f * repl);
    }
    out[0] = base;
  }
}

// K4: pairwise exp-kernel sums via MFMA: d2 = qn_i + qn_j - 2*dot(i,j).
// 1536 blocks = type(3) x class(8) x rtile(8) x ctile(8); 32x32 tile/block,
// 4 waves each own a 16x16 subtile (mfma_f32_16x16x32_bf16, K-loop of 8).
// Operands loaded straight from global f32 (L2-resident), cvt to bf16 on
// the fly; A and B frags use the identical per-lane pattern so the HW's
// internal k-permutation cancels. C/D: col=lane&15, row=(lane>>4)*4+reg.
__global__ __launch_bounds__(256) void k4_pairs(
    const float* __restrict__ cfeat, const float* __restrict__ nfeat,
    const char* __restrict__ ws, float* __restrict__ out) {
  __shared__ float shred[4];
  int bid = blockIdx.x;
  int type  = bid >> 9;
  int c     = (bid >> 6) & 7;
  int rtile = (bid >> 3) & 7;
  int ctile = bid & 7;
  if (type <= 1 && ctile < rtile) return;   // symmetric types: upper only

  const int* cnt_s = (const int*)(ws + OFF_CNT_S);
  const int* cnt_t = (const int*)(ws + OFF_CNT_T);
  const int* idx_s = (const int*)(ws + OFF_IDX_S);
  const int* idx_t = (const int*)(ws + OFF_IDX_T);
  const float* wt  = (const float*)(ws + OFF_WT);
  const float* scc = (const float*)(ws + OFF_SCC);
  const float* snn = (const float*)(ws + OFF_SNN);
  const float* scn = (const float*)(ws + OFF_SCN);
  const float* invbw = (const float*)(ws + OFF_INVBW);
  const float* qnS = (const float*)(ws + OFF_QNS);
  const float* qnT = (const float*)(ws + OFF_QNT);

  const int* pa; const int* pb;
  const float* fa; const float* fb;
  const float* qa_; const float* qb_;
  const float* wa = nullptr; const float* wb = nullptr;
  int na, nb; float scale;
  if (type == 0) {
    pa = idx_s + c * NN; pb = pa; na = nb = cnt_s[c];
    fa = cfeat; fb = cfeat; qa_ = qnS + c * NN; qb_ = qa_; scale = scc[c];
  } else if (type == 1) {
    pa = idx_t + c * NN; pb = pa; na = nb = cnt_t[c];
    fa = nfeat; fb = nfeat; qa_ = qnT + c * NN; qb_ = qa_;
    wa = wt + c * NN; wb = wa; scale = snn[c];
  } else {
    pa = idx_s + c * NN; na = cnt_s[c];
    pb = idx_t + c * NN; nb = cnt_t[c];
    fa = cfeat; fb = nfeat; qa_ = qnS + c * NN; qb_ = qnT + c * NN;
    wb = wt + c * NN; scale = scn[c];
  }
  int rbase = rtile * 32, cbase = ctile * 32;
  if (scale == 0.f || rbase >= na || cbase >= nb) return;
  float factor = (type <= 1 && ctile > rtile) ? 2.f : 1.f;

  float ib0 = invbw[c * 5 + 0], ib1 = invbw[c * 5 + 1], ib2 = invbw[c * 5 + 2];
  float ib3 = invbw[c * 5 + 3], ib4 = invbw[c * 5 + 4];

  int w = threadIdx.x >> 6, l = threadIdx.x & 63;
  int sr = (w >> 1) * 16, sc = (w & 1) * 16;
  int posA = rbase + sr + (l & 15);
  int posB = cbase + sc + (l & 15);
  int pAc = posA < na ? posA : (na - 1);
  int pBc = posB < nb ? posB : (nb - 1);
  const float* rowA = fa + (long)pa[pAc] * DD + (l >> 4) * 8;
  const float* rowB = fb + (long)pb[pBc] * DD + (l >> 4) * 8;

  f32x4 acc = {0.f, 0.f, 0.f, 0.f};
#pragma unroll
  for (int ks = 0; ks < 8; ++ks) {
    float4 a0 = *(const float4*)(rowA + ks * 32);
    float4 a1 = *(const float4*)(rowA + ks * 32 + 4);
    float4 b0 = *(const float4*)(rowB + ks * 32);
    float4 b1 = *(const float4*)(rowB + ks * 32 + 4);
    bf16x8 af, bf;
    af[0] = f2bf(a0.x); af[1] = f2bf(a0.y); af[2] = f2bf(a0.z); af[3] = f2bf(a0.w);
    af[4] = f2bf(a1.x); af[5] = f2bf(a1.y); af[6] = f2bf(a1.z); af[7] = f2bf(a1.w);
    bf[0] = f2bf(b0.x); bf[1] = f2bf(b0.y); bf[2] = f2bf(b0.z); bf[3] = f2bf(b0.w);
    bf[4] = f2bf(b1.x); bf[5] = f2bf(b1.y); bf[6] = f2bf(b1.z); bf[7] = f2bf(b1.w);
    acc = __builtin_amdgcn_mfma_f32_16x16x32_bf16(af, bf, acc, 0, 0, 0);
  }

  // epilogue: lane holds D[row][col] for col = sc+(l&15), row = sr+(l>>4)*4+r
  bool jval = (posB < nb);
  float knj = qb_[pBc];
  float wj = (type == 0) ? 1.f : wb[pBc];
  int rowbase = rbase + sr + ((l >> 4) << 2);          // 16B-aligned
  f32x4 qA4 = *(const f32x4*)&qa_[rowbase];
  f32x4 wA4 = {1.f, 1.f, 1.f, 1.f};
  if (type == 1) wA4 = *(const f32x4*)&wa[rowbase];

  float partial = 0.f;
#pragma unroll
  for (int r = 0; r < 4; ++r) {
    int ipos = rowbase + r;
    bool val = jval && (ipos < na);
    float d2 = fmaxf(qA4[r] + knj - 2.f * acc[r], 0.f);
    float e = __expf(-d2 * ib0) + __expf(-d2 * ib1) + __expf(-d2 * ib2)
            + __expf(-d2 * ib3) + __expf(-d2 * ib4);
    float wgt = (type == 1) ? wA4[r] * wj : wj;
    partial += val ? wgt * e : 0.f;
  }
  partial = wred64(partial);
  if (l == 0) shred[w] = partial;
  __syncthreads();
  if (threadIdx.x == 0) {
    float tot = shred[0] + shred[1] + shred[2] + shred[3];
    atomicAdd(out, scale * factor * tot);
  }
}

extern "C" void kernel_launch(void* const* d_in, const int* in_sizes, int n_in,
                              void* d_out, int out_size, void* d_ws, size_t ws_size,
                              hipStream_t stream) {
  const float* cfeat  = (const float*)d_in[0];
  const float* nfeat  = (const float*)d_in[1];
  const int*   clab   = (const int*)d_in[2];
  const int*   nlab   = (const int*)d_in[3];
  const float* nmask  = (const float*)d_in[4];
  const float* nscore = (const float*)d_in[5];
  const float* cw     = (const float*)d_in[6];
  float* out = (float*)d_out;
  char* ws = (char*)d_ws;

  k1_lists<<<1, 512, 0, stream>>>(clab, nlab, nmask, nscore, ws);
  k2_moments<<<256, 256, 0, stream>>>(cfeat, nfeat, ws);
  k3_finalize<<<1, 256, 0, stream>>>(cw, ws, out);
  k4_pairs<<<3 * 8 * 64, 256, 0, stream>>>(cfeat, nfeat, ws, out);
}